// Round 1
// baseline (202.073 us; speedup 1.0000x reference)
//
#include <hip/hip_runtime.h>
#include <hip/hip_bf16.h>

typedef __attribute__((ext_vector_type(4))) float f32x4;
typedef __attribute__((ext_vector_type(8))) short s16x8;
typedef __attribute__((ext_vector_type(4))) short s16x4;

#define BB 2
#define NN 2048
#define HH 1024
#define NHEAD 16
#define HDIM 64

__device__ __forceinline__ short f2bf(float f) {
  union { float f; unsigned u; } v; v.f = f;
  unsigned r = v.u + 0x7fffu + ((v.u >> 16) & 1u);
  return (short)(r >> 16);
}

__device__ __forceinline__ f32x4 zf4() { f32x4 z; z[0]=0.f; z[1]=0.f; z[2]=0.f; z[3]=0.f; return z; }

__device__ __forceinline__ f32x4 mfma16(s16x8 a, s16x8 b, f32x4 c) {
  return __builtin_amdgcn_mfma_f32_16x16x32_bf16(a, b, c, 0, 0, 0);
}

__device__ __forceinline__ s16x4 cvt4(f32x4 v) {
  s16x4 o; o[0]=f2bf(v[0]); o[1]=f2bf(v[1]); o[2]=f2bf(v[2]); o[3]=f2bf(v[3]); return o;
}

// ---------------- prep: fp32->bf16 conversions + rope tables ----------------
__global__ __launch_bounds__(256) void prep_kernel(
    const float* __restrict__ feat,
    const float* __restrict__ wq, const float* __restrict__ wk,
    const float* __restrict__ wv, const float* __restrict__ wo,
    short* __restrict__ fbf, short* __restrict__ wqb, short* __restrict__ wkb,
    short* __restrict__ wvb, short* __restrict__ wob,
    float* __restrict__ cosb, float* __restrict__ sinb) {
  const int tid = blockIdx.x * blockDim.x + threadIdx.x;
  const int nth = gridDim.x * blockDim.x;
  const int NF4 = BB*NN*HH/4;
  for (int i = tid; i < NF4; i += nth)
    ((s16x4*)fbf)[i] = cvt4(((const f32x4*)feat)[i]);
  const int NW4 = HH*HH/4;
  for (int i = tid; i < NW4; i += nth) {
    ((s16x4*)wqb)[i] = cvt4(((const f32x4*)wq)[i]);
    ((s16x4*)wkb)[i] = cvt4(((const f32x4*)wk)[i]);
    ((s16x4*)wvb)[i] = cvt4(((const f32x4*)wv)[i]);
    ((s16x4*)wob)[i] = cvt4(((const f32x4*)wo)[i]);
  }
  // rope table: cos/sin[pos][f], f in [0,32), inv_freq = 10000^(-f/32)
  for (int i = tid; i < NN*32; i += nth) {
    int pos = i >> 5, f = i & 31;
    float inv = __expf(-(float)f * 0.28782313662425572f);  // ln(10000)/32
    float ang = (float)pos * inv;
    float s, c;
    sincosf(ang, &s, &c);
    cosb[i] = c; sinb[i] = s;
  }
}

// ---------------- GEMM core: C = A(bf16 [M,1024]) @ W^T (W bf16 [1024,1024] row-major [o][k]) ----
// 256 threads, tile 128x128, BK=32, waves 2x2, per-wave 64x64 (4x4 frags of 16x16x32)
// smem usage: A_t [128][40] + B_t [128][40] = 10240 shorts
__device__ __forceinline__ void gemm128_core(
    const short* __restrict__ A, const short* __restrict__ W,
    int bm, int bn, short* smem, f32x4 acc[4][4]) {
  const int tid = threadIdx.x;
  const int lane = tid & 63, wid = tid >> 6;
  const int wr = wid >> 1, wc = wid & 1;
  const int g = lane >> 4, lr = lane & 15;
  short* At = smem;          // [128][40]
  short* Bt = smem + 5120;   // [128][40]
#pragma unroll
  for (int i = 0; i < 4; ++i)
#pragma unroll
    for (int j = 0; j < 4; ++j) acc[i][j] = zf4();

  const int srow = tid >> 2;        // 0..63
  const int scol = (tid & 3) * 8;   // 0,8,16,24
  const short* Aptr = A + (size_t)(bm*128 + srow) * HH + scol;
  const short* Wptr = W + (size_t)(bn*128 + srow) * HH + scol;

  s16x8 ra0 = *(const s16x8*)(Aptr);
  s16x8 ra1 = *(const s16x8*)(Aptr + 64*HH);
  s16x8 rb0 = *(const s16x8*)(Wptr);
  s16x8 rb1 = *(const s16x8*)(Wptr + 64*HH);

  const int NT = HH / 32;
  for (int t = 0; t < NT; ++t) {
    *(s16x8*)&At[srow*40 + scol]      = ra0;
    *(s16x8*)&At[(srow+64)*40 + scol] = ra1;
    *(s16x8*)&Bt[srow*40 + scol]      = rb0;
    *(s16x8*)&Bt[(srow+64)*40 + scol] = rb1;
    __syncthreads();
    if (t + 1 < NT) {  // prefetch next K-slab into regs; overlaps MFMA below
      const short* ap = Aptr + (t+1)*32;
      const short* wp = Wptr + (t+1)*32;
      ra0 = *(const s16x8*)(ap);
      ra1 = *(const s16x8*)(ap + 64*HH);
      rb0 = *(const s16x8*)(wp);
      rb1 = *(const s16x8*)(wp + 64*HH);
    }
    s16x8 af[4], bf[4];
#pragma unroll
    for (int mf = 0; mf < 4; ++mf)
      af[mf] = *(const s16x8*)&At[(wr*64 + mf*16 + lr)*40 + g*8];
#pragma unroll
    for (int nf = 0; nf < 4; ++nf)
      bf[nf] = *(const s16x8*)&Bt[(wc*64 + nf*16 + lr)*40 + g*8];
#pragma unroll
    for (int mf = 0; mf < 4; ++mf)
#pragma unroll
      for (int nf = 0; nf < 4; ++nf)
        acc[mf][nf] = mfma16(af[mf], bf[nf], acc[mf][nf]);
    __syncthreads();
  }
}

// ---------------- QKV projection + RoPE + layout ----------------
// z=0: Q (rope, *0.125) -> [b,h,n,d] ; z=1: K (rope) -> [b,h,n,d] ; z=2: V -> V^T [b,h,d,n]
__global__ __launch_bounds__(256) void qkv_kernel(
    const short* __restrict__ fbf, const short* __restrict__ wqb,
    const short* __restrict__ wkb, const short* __restrict__ wvb,
    const float* __restrict__ cosb, const float* __restrict__ sinb,
    short* __restrict__ qb, short* __restrict__ kb, short* __restrict__ vtb) {
  __shared__ short smem[18432];
  const int bm = blockIdx.y, bn = blockIdx.x, z = blockIdx.z;
  const short* W = (z == 0) ? wqb : ((z == 1) ? wkb : wvb);
  f32x4 acc[4][4];
  gemm128_core(fbf, W, bm, bn, smem, acc);

  const int tid = threadIdx.x, lane = tid & 63, wid = tid >> 6;
  const int wr = wid >> 1, wc = wid & 1, g = lane >> 4, lr = lane & 15;
  const int head = bn*2 + wc;
  const int m0 = bm*128 + wr*64;
  const int b = m0 / NN;

  if (z < 2) {
    short* dst = (z == 0) ? qb : kb;
    const float scale = (z == 0) ? 0.125f : 1.0f;  // fold 1/sqrt(d) into Q
#pragma unroll
    for (int mf = 0; mf < 4; ++mf) {
#pragma unroll
      for (int r = 0; r < 4; ++r) {
        int m = m0 + mf*16 + g*4 + r;
        int n = m & (NN - 1);
        float c0 = cosb[n*32 + lr],      s0 = sinb[n*32 + lr];
        float c1 = cosb[n*32 + 16 + lr], s1 = sinb[n*32 + 16 + lr];
        float v0 = acc[mf][0][r], v1 = acc[mf][1][r];
        float v2 = acc[mf][2][r], v3 = acc[mf][3][r];
        float o0 = (v0*c0 - v2*s0) * scale;
        float o1 = (v1*c1 - v3*s1) * scale;
        float o2 = (v2*c0 + v0*s0) * scale;
        float o3 = (v3*c1 + v1*s1) * scale;
        size_t base = ((size_t)(b*NHEAD + head)*NN + n)*HDIM;
        dst[base +  0 + lr] = f2bf(o0);
        dst[base + 16 + lr] = f2bf(o1);
        dst[base + 32 + lr] = f2bf(o2);
        dst[base + 48 + lr] = f2bf(o3);
      }
    }
  } else {
    // V: transpose 64x64 wave tile via LDS, write V^T rows (coalesced 16B)
    __syncthreads();
    short* tp = smem + wid*4608;  // [64][72]
#pragma unroll
    for (int mf = 0; mf < 4; ++mf)
#pragma unroll
      for (int nf = 0; nf < 4; ++nf)
#pragma unroll
        for (int r = 0; r < 4; ++r)
          tp[(nf*16 + lr)*72 + mf*16 + g*4 + r] = f2bf(acc[mf][nf][r]);
    __syncthreads();
    const int nbase = m0 & (NN - 1);
    size_t vbase = ((size_t)(b*NHEAD + head)*HDIM)*NN;
#pragma unroll
    for (int it = 0; it < 8; ++it) {
      int j  = it*8 + (lane >> 3);
      int ns = (lane & 7)*8;
      s16x8 vv = *(const s16x8*)&tp[j*72 + ns];
      *(s16x8*)&vtb[vbase + (size_t)j*NN + nbase + ns] = vv;
    }
  }
}

// ---------------- fused flash attention ----------------
// grid: (N/64, B*NHEAD); 4 waves, each 16 q rows; 32-key steps
__global__ __launch_bounds__(256) void attn_kernel(
    const short* __restrict__ qb, const short* __restrict__ kb,
    const short* __restrict__ vtb, const int* __restrict__ mask,
    short* __restrict__ attnb) {
  __shared__ short Kt[32*72];      // [32 keys][64 d + pad]
  __shared__ short Vt[64*40];      // [64 d][32 keys + pad]
  __shared__ short Pt[4][16*40];   // per-wave [16 q][32 keys + pad]
  const int tid = threadIdx.x, lane = tid & 63, wid = tid >> 6;
  const int g = lane >> 4, lr = lane & 15;
  const int bh = blockIdx.y; const int b = bh >> 4;
  const int q0 = blockIdx.x*64 + wid*16;

  // Q fragments (A-operand): row = lr, d = kk*32 + g*8 .. +8
  const short* qp = qb + ((size_t)bh*NN + q0 + lr)*HDIM + g*8;
  s16x8 qf0 = *(const s16x8*)(qp);
  s16x8 qf1 = *(const s16x8*)(qp + 32);

  f32x4 acc[4];
#pragma unroll
  for (int i = 0; i < 4; ++i) acc[i] = zf4();
  float mrun[4], lsum[4];
#pragma unroll
  for (int r = 0; r < 4; ++r) { mrun[r] = -3.0e38f; lsum[r] = 0.f; }

  const int srowK = tid >> 3, ssegK = (tid & 7)*8;  // K stage rows 0..31
  const int srowV = tid >> 2, ssegV = (tid & 3)*8;  // Vt stage rows 0..63
  const short* kp = kb + (size_t)bh*NN*HDIM + (size_t)srowK*HDIM + ssegK;
  const short* vp = vtb + ((size_t)bh*HDIM + srowV)*NN + ssegV;
  const int* mp = mask + b*NN;

  for (int k0 = 0; k0 < NN; k0 += 32) {
    s16x8 kv = *(const s16x8*)(kp + (size_t)k0*HDIM);
    s16x8 vv = *(const s16x8*)(vp + k0);
    *(s16x8*)&Kt[srowK*72 + ssegK] = kv;
    *(s16x8*)&Vt[srowV*40 + ssegV] = vv;
    __syncthreads();

    // scores S[16q x 32keys] = Q @ K^T (per-wave)
    f32x4 s0 = zf4(), s1 = zf4();
    s16x8 kb0 = *(const s16x8*)&Kt[lr*72 + g*8];
    s16x8 kb1 = *(const s16x8*)&Kt[lr*72 + 32 + g*8];
    s16x8 kb2 = *(const s16x8*)&Kt[(16 + lr)*72 + g*8];
    s16x8 kb3 = *(const s16x8*)&Kt[(16 + lr)*72 + 32 + g*8];
    s0 = mfma16(qf0, kb0, s0); s0 = mfma16(qf1, kb1, s0);
    s1 = mfma16(qf0, kb2, s1); s1 = mfma16(qf1, kb3, s1);

    int mk0 = mp[k0 + lr], mk1 = mp[k0 + 16 + lr];
    float sm0[4], sm1[4], rmax[4];
#pragma unroll
    for (int r = 0; r < 4; ++r) {
      sm0[r] = mk0 ? s0[r] : -3.0e38f;
      sm1[r] = mk1 ? s1[r] : -3.0e38f;
      rmax[r] = fmaxf(sm0[r], sm1[r]);
    }
#pragma unroll
    for (int off = 1; off < 16; off <<= 1)
#pragma unroll
      for (int r = 0; r < 4; ++r)
        rmax[r] = fmaxf(rmax[r], __shfl_xor(rmax[r], off));
    float al[4], p0[4], p1[4];
#pragma unroll
    for (int r = 0; r < 4; ++r) {
      float mnew = fmaxf(mrun[r], rmax[r]);
      al[r] = __expf(mrun[r] - mnew);
      mrun[r] = mnew;
      p0[r] = mk0 ? __expf(sm0[r] - mnew) : 0.f;
      p1[r] = mk1 ? __expf(sm1[r] - mnew) : 0.f;
      lsum[r] = lsum[r]*al[r] + p0[r] + p1[r];
    }
#pragma unroll
    for (int db = 0; db < 4; ++db)
#pragma unroll
      for (int r = 0; r < 4; ++r)
        acc[db][r] *= al[r];

    // P: C-layout -> A-layout via per-wave LDS
#pragma unroll
    for (int r = 0; r < 4; ++r) {
      Pt[wid][(g*4 + r)*40 + lr]      = f2bf(p0[r]);
      Pt[wid][(g*4 + r)*40 + 16 + lr] = f2bf(p1[r]);
    }
    s16x8 pa = *(const s16x8*)&Pt[wid][lr*40 + g*8];
#pragma unroll
    for (int db = 0; db < 4; ++db) {
      s16x8 vb = *(const s16x8*)&Vt[(db*16 + lr)*40 + g*8];
      acc[db] = mfma16(pa, vb, acc[db]);
    }
    __syncthreads();
  }

#pragma unroll
  for (int off = 1; off < 16; off <<= 1)
#pragma unroll
    for (int r = 0; r < 4; ++r)
      lsum[r] += __shfl_xor(lsum[r], off);

#pragma unroll
  for (int r = 0; r < 4; ++r) {
    float inv = 1.0f / lsum[r];
    size_t row = (size_t)(b*NN + q0 + g*4 + r);
#pragma unroll
    for (int db = 0; db < 4; ++db)
      attnb[row*HH + (bh & 15)*64 + db*16 + lr] = f2bf(acc[db][r]*inv);
  }
}

// ---------------- output projection (fp32 out) ----------------
__global__ __launch_bounds__(256) void outproj_kernel(
    const short* __restrict__ attnb, const short* __restrict__ wob,
    float* __restrict__ out) {
  __shared__ short smem[10240];
  const int bm = blockIdx.y, bn = blockIdx.x;
  f32x4 acc[4][4];
  gemm128_core(attnb, wob, bm, bn, smem, acc);
  const int tid = threadIdx.x, lane = tid & 63, wid = tid >> 6;
  const int wr = wid >> 1, wc = wid & 1, g = lane >> 4, lr = lane & 15;
  const int m0 = bm*128 + wr*64;
  const int c0 = bn*128 + wc*64;
#pragma unroll
  for (int mf = 0; mf < 4; ++mf)
#pragma unroll
    for (int r = 0; r < 4; ++r) {
      int m = m0 + mf*16 + g*4 + r;
      float* po = out + (size_t)m*HH + c0;
#pragma unroll
      for (int nf = 0; nf < 4; ++nf)
        po[nf*16 + lr] = acc[mf][nf][r];
    }
}

extern "C" void kernel_launch(void* const* d_in, const int* in_sizes, int n_in,
                              void* d_out, int out_size, void* d_ws, size_t ws_size,
                              hipStream_t stream) {
  const float* feat = (const float*)d_in[0];
  const int*   mask = (const int*)d_in[1];
  const float* wq   = (const float*)d_in[2];
  const float* wk   = (const float*)d_in[3];
  const float* wv   = (const float*)d_in[4];
  const float* wo   = (const float*)d_in[5];
  float* out = (float*)d_out;

  char* ws = (char*)d_ws;
  size_t off = 0;
  short* fbf = (short*)(ws + off); off += (size_t)BB*NN*HH*2;   // 8 MB
  short* wqb = (short*)(ws + off); off += (size_t)HH*HH*2;
  short* wkb = (short*)(ws + off); off += (size_t)HH*HH*2;
  short* wvb = (short*)(ws + off); off += (size_t)HH*HH*2;
  short* wob = (short*)(ws + off); off += (size_t)HH*HH*2;
  float* cosb = (float*)(ws + off); off += (size_t)NN*32*4;
  float* sinb = (float*)(ws + off); off += (size_t)NN*32*4;
  short* qbuf = (short*)(ws + off); off += (size_t)BB*NN*HH*2;
  short* kbuf = (short*)(ws + off); off += (size_t)BB*NN*HH*2;
  short* vtbuf = (short*)(ws + off); off += (size_t)BB*NN*HH*2;
  short* attnb = (short*)(ws + off); off += (size_t)BB*NN*HH*2;

  prep_kernel<<<1024, 256, 0, stream>>>(feat, wq, wk, wv, wo,
                                        fbf, wqb, wkb, wvb, wob, cosb, sinb);
  qkv_kernel<<<dim3(HH/128, BB*NN/128, 3), 256, 0, stream>>>(
      fbf, wqb, wkb, wvb, cosb, sinb, qbuf, kbuf, vtbuf);
  attn_kernel<<<dim3(NN/64, BB*NHEAD), 256, 0, stream>>>(
      qbuf, kbuf, vtbuf, mask, attnb);
  outproj_kernel<<<dim3(HH/128, BB*NN/128), 256, 0, stream>>>(attnb, wob, out);
}

// Round 2
// 165.721 us; speedup vs baseline: 1.2194x; 1.2194x over previous
//
#include <hip/hip_runtime.h>
#include <hip/hip_bf16.h>

typedef __attribute__((ext_vector_type(4))) float f32x4;
typedef __attribute__((ext_vector_type(8))) short s16x8;
typedef __attribute__((ext_vector_type(4))) short s16x4;

#define BB 2
#define NN 2048
#define HH 1024
#define NHEAD 16
#define HDIM 64

__device__ __forceinline__ short f2bf(float f) {
  union { float f; unsigned u; } v; v.f = f;
  unsigned r = v.u + 0x7fffu + ((v.u >> 16) & 1u);
  return (short)(r >> 16);
}

__device__ __forceinline__ f32x4 zf4() { f32x4 z; z[0]=0.f; z[1]=0.f; z[2]=0.f; z[3]=0.f; return z; }

__device__ __forceinline__ f32x4 mfma16(s16x8 a, s16x8 b, f32x4 c) {
  return __builtin_amdgcn_mfma_f32_16x16x32_bf16(a, b, c, 0, 0, 0);
}

__device__ __forceinline__ s16x4 cvt4(f32x4 v) {
  s16x4 o; o[0]=f2bf(v[0]); o[1]=f2bf(v[1]); o[2]=f2bf(v[2]); o[3]=f2bf(v[3]); return o;
}

__device__ __forceinline__ float vexp2(float x) {
  float r; asm("v_exp_f32 %0, %1" : "=v"(r) : "v"(x)); return r;
}

__device__ __forceinline__ unsigned cvtpk_bf16(float lo, float hi) {
  unsigned r; asm("v_cvt_pk_bf16_f32 %0, %1, %2" : "=v"(r) : "v"(lo), "v"(hi)); return r;
}

// ---------------- prep: fp32->bf16 conversions + rope tables + mask bias ----------------
__global__ __launch_bounds__(256) void prep_kernel(
    const float* __restrict__ feat, const int* __restrict__ mask,
    const float* __restrict__ wq, const float* __restrict__ wk,
    const float* __restrict__ wv, const float* __restrict__ wo,
    short* __restrict__ fbf, short* __restrict__ wqb, short* __restrict__ wkb,
    short* __restrict__ wvb, short* __restrict__ wob,
    float* __restrict__ cosb, float* __restrict__ sinb,
    float* __restrict__ mbias) {
  const int tid = blockIdx.x * blockDim.x + threadIdx.x;
  const int nth = gridDim.x * blockDim.x;
  const int NF4 = BB*NN*HH/4;
  for (int i = tid; i < NF4; i += nth)
    ((s16x4*)fbf)[i] = cvt4(((const f32x4*)feat)[i]);
  const int NW4 = HH*HH/4;
  for (int i = tid; i < NW4; i += nth) {
    ((s16x4*)wqb)[i] = cvt4(((const f32x4*)wq)[i]);
    ((s16x4*)wkb)[i] = cvt4(((const f32x4*)wk)[i]);
    ((s16x4*)wvb)[i] = cvt4(((const f32x4*)wv)[i]);
    ((s16x4*)wob)[i] = cvt4(((const f32x4*)wo)[i]);
  }
  // rope table: cos/sin[pos][f], f in [0,32), inv_freq = 10000^(-f/32)
  for (int i = tid; i < NN*32; i += nth) {
    int pos = i >> 5, f = i & 31;
    float inv = __expf(-(float)f * 0.28782313662425572f);  // ln(10000)/32
    float ang = (float)pos * inv;
    float s, c;
    sincosf(ang, &s, &c);
    cosb[i] = c; sinb[i] = s;
  }
  // mask bias: 0 if valid, -1e30 if masked (finite so s-m never cancels to 0)
  for (int i = tid; i < BB*NN; i += nth)
    mbias[i] = mask[i] ? 0.f : -1.0e30f;
}

// ---------------- GEMM core: C = A(bf16 [M,1024]) @ W^T (W bf16 [1024,1024] row-major [o][k]) ----
__device__ __forceinline__ void gemm128_core(
    const short* __restrict__ A, const short* __restrict__ W,
    int bm, int bn, short* smem, f32x4 acc[4][4]) {
  const int tid = threadIdx.x;
  const int lane = tid & 63, wid = tid >> 6;
  const int wr = wid >> 1, wc = wid & 1;
  const int g = lane >> 4, lr = lane & 15;
  short* At = smem;          // [128][40]
  short* Bt = smem + 5120;   // [128][40]
#pragma unroll
  for (int i = 0; i < 4; ++i)
#pragma unroll
    for (int j = 0; j < 4; ++j) acc[i][j] = zf4();

  const int srow = tid >> 2;        // 0..63
  const int scol = (tid & 3) * 8;   // 0,8,16,24
  const short* Aptr = A + (size_t)(bm*128 + srow) * HH + scol;
  const short* Wptr = W + (size_t)(bn*128 + srow) * HH + scol;

  s16x8 ra0 = *(const s16x8*)(Aptr);
  s16x8 ra1 = *(const s16x8*)(Aptr + 64*HH);
  s16x8 rb0 = *(const s16x8*)(Wptr);
  s16x8 rb1 = *(const s16x8*)(Wptr + 64*HH);

  const int NT = HH / 32;
  for (int t = 0; t < NT; ++t) {
    *(s16x8*)&At[srow*40 + scol]      = ra0;
    *(s16x8*)&At[(srow+64)*40 + scol] = ra1;
    *(s16x8*)&Bt[srow*40 + scol]      = rb0;
    *(s16x8*)&Bt[(srow+64)*40 + scol] = rb1;
    __syncthreads();
    if (t + 1 < NT) {
      const short* ap = Aptr + (t+1)*32;
      const short* wp = Wptr + (t+1)*32;
      ra0 = *(const s16x8*)(ap);
      ra1 = *(const s16x8*)(ap + 64*HH);
      rb0 = *(const s16x8*)(wp);
      rb1 = *(const s16x8*)(wp + 64*HH);
    }
    s16x8 af[4], bf[4];
#pragma unroll
    for (int mf = 0; mf < 4; ++mf)
      af[mf] = *(const s16x8*)&At[(wr*64 + mf*16 + lr)*40 + g*8];
#pragma unroll
    for (int nf = 0; nf < 4; ++nf)
      bf[nf] = *(const s16x8*)&Bt[(wc*64 + nf*16 + lr)*40 + g*8];
#pragma unroll
    for (int mf = 0; mf < 4; ++mf)
#pragma unroll
      for (int nf = 0; nf < 4; ++nf)
        acc[mf][nf] = mfma16(af[mf], bf[nf], acc[mf][nf]);
    __syncthreads();
  }
}

// ---------------- QKV projection + RoPE + layout ----------------
// z=0: Q (rope, *0.125*log2e) -> [b,h,n,d] ; z=1: K (rope) -> [b,h,n,d] ; z=2: V -> V^T [b,h,d,n]
__global__ __launch_bounds__(256) void qkv_kernel(
    const short* __restrict__ fbf, const short* __restrict__ wqb,
    const short* __restrict__ wkb, const short* __restrict__ wvb,
    const float* __restrict__ cosb, const float* __restrict__ sinb,
    short* __restrict__ qb, short* __restrict__ kb, short* __restrict__ vtb) {
  __shared__ short smem[18432];
  const int bm = blockIdx.y, bn = blockIdx.x, z = blockIdx.z;
  const short* W = (z == 0) ? wqb : ((z == 1) ? wkb : wvb);
  f32x4 acc[4][4];
  gemm128_core(fbf, W, bm, bn, smem, acc);

  const int tid = threadIdx.x, lane = tid & 63, wid = tid >> 6;
  const int wr = wid >> 1, wc = wid & 1, g = lane >> 4, lr = lane & 15;
  const int head = bn*2 + wc;
  const int m0 = bm*128 + wr*64;
  const int b = m0 / NN;

  if (z < 2) {
    short* dst = (z == 0) ? qb : kb;
    // Q: fold 1/sqrt(d) AND log2(e) (we use exp2 in attention)
    const float scale = (z == 0) ? 0.18033688011112042f : 1.0f;
#pragma unroll
    for (int mf = 0; mf < 4; ++mf) {
#pragma unroll
      for (int r = 0; r < 4; ++r) {
        int m = m0 + mf*16 + g*4 + r;
        int n = m & (NN - 1);
        float c0 = cosb[n*32 + lr],      s0 = sinb[n*32 + lr];
        float c1 = cosb[n*32 + 16 + lr], s1 = sinb[n*32 + 16 + lr];
        float v0 = acc[mf][0][r], v1 = acc[mf][1][r];
        float v2 = acc[mf][2][r], v3 = acc[mf][3][r];
        float o0 = (v0*c0 - v2*s0) * scale;
        float o1 = (v1*c1 - v3*s1) * scale;
        float o2 = (v2*c0 + v0*s0) * scale;
        float o3 = (v3*c1 + v1*s1) * scale;
        size_t base = ((size_t)(b*NHEAD + head)*NN + n)*HDIM;
        dst[base +  0 + lr] = f2bf(o0);
        dst[base + 16 + lr] = f2bf(o1);
        dst[base + 32 + lr] = f2bf(o2);
        dst[base + 48 + lr] = f2bf(o3);
      }
    }
  } else {
    __syncthreads();
    short* tp = smem + wid*4608;  // [64][72]
#pragma unroll
    for (int mf = 0; mf < 4; ++mf)
#pragma unroll
      for (int nf = 0; nf < 4; ++nf)
#pragma unroll
        for (int r = 0; r < 4; ++r)
          tp[(nf*16 + lr)*72 + mf*16 + g*4 + r] = f2bf(acc[mf][nf][r]);
    __syncthreads();
    const int nbase = m0 & (NN - 1);
    size_t vbase = ((size_t)(b*NHEAD + head)*HDIM)*NN;
#pragma unroll
    for (int it = 0; it < 8; ++it) {
      int j  = it*8 + (lane >> 3);
      int ns = (lane & 7)*8;
      s16x8 vv = *(const s16x8*)&tp[j*72 + ns];
      *(s16x8*)&vtb[vbase + (size_t)j*NN + nbase + ns] = vv;
    }
  }
}

// ---------------- fused flash attention ----------------
// grid: (N/64, B*NHEAD); 4 waves, each 16 q rows; 64-key steps
__global__ __launch_bounds__(256) void attn_kernel(
    const short* __restrict__ qb, const short* __restrict__ kb,
    const short* __restrict__ vtb, const float* __restrict__ mbias,
    short* __restrict__ attnb) {
  __shared__ short Kt[64*72];      // [64 keys][64 d + pad]
  __shared__ short Vt[64*72];      // [64 d][64 keys + pad]
  __shared__ short Pt[4][16*72];   // per-wave [16 q][64 keys + pad]
  const int tid = threadIdx.x, lane = tid & 63, wid = tid >> 6;
  const int g = lane >> 4, lr = lane & 15;
  const int bh = blockIdx.y; const int b = bh >> 4;
  const int q0 = blockIdx.x*64 + wid*16;

  const short* qp = qb + ((size_t)bh*NN + q0 + lr)*HDIM + g*8;
  s16x8 qf0 = *(const s16x8*)(qp);
  s16x8 qf1 = *(const s16x8*)(qp + 32);

  f32x4 acc[4];
#pragma unroll
  for (int i = 0; i < 4; ++i) acc[i] = zf4();
  float mrun[4], lsum[4];
#pragma unroll
  for (int r = 0; r < 4; ++r) { mrun[r] = -3.0e38f; lsum[r] = 0.f; }

  const int sr = tid >> 2;            // 0..63
  const int sc = (tid & 3) * 16;      // 0,16,32,48
  const short* kp = kb + (size_t)bh*NN*HDIM + (size_t)sr*HDIM + sc;
  const short* vp = vtb + ((size_t)bh*HDIM + sr)*NN + sc;
  const float* mb = mbias + b*NN;

  s16x8 kr0 = *(const s16x8*)(kp);
  s16x8 kr1 = *(const s16x8*)(kp + 8);
  s16x8 vr0 = *(const s16x8*)(vp);
  s16x8 vr1 = *(const s16x8*)(vp + 8);

  for (int k0 = 0; k0 < NN; k0 += 64) {
    *(s16x8*)&Kt[sr*72 + sc]     = kr0;
    *(s16x8*)&Kt[sr*72 + sc + 8] = kr1;
    *(s16x8*)&Vt[sr*72 + sc]     = vr0;
    *(s16x8*)&Vt[sr*72 + sc + 8] = vr1;
    __syncthreads();
    if (k0 + 64 < NN) {  // prefetch next tile into regs (overlaps compute)
      kp += 64*HDIM; vp += 64;
      kr0 = *(const s16x8*)(kp);
      kr1 = *(const s16x8*)(kp + 8);
      vr0 = *(const s16x8*)(vp);
      vr1 = *(const s16x8*)(vp + 8);
    }

    // scores S[16q x 64keys] in 4 key-groups; add mask bias
    float bia0 = mb[k0 + lr], bia1 = mb[k0 + 16 + lr];
    float bia2 = mb[k0 + 32 + lr], bia3 = mb[k0 + 48 + lr];
    f32x4 s[4];
#pragma unroll
    for (int kg = 0; kg < 4; ++kg) {
      s16x8 kb0 = *(const s16x8*)&Kt[(kg*16 + lr)*72 + g*8];
      s16x8 kb1 = *(const s16x8*)&Kt[(kg*16 + lr)*72 + 32 + g*8];
      f32x4 t = zf4();
      t = mfma16(qf0, kb0, t);
      t = mfma16(qf1, kb1, t);
      float bi = (kg == 0) ? bia0 : (kg == 1) ? bia1 : (kg == 2) ? bia2 : bia3;
#pragma unroll
      for (int r = 0; r < 4; ++r) t[r] += bi;
      s[kg] = t;
    }

    // row max (in-reg over 4 groups, then across 16 lanes)
    float rmax[4];
#pragma unroll
    for (int r = 0; r < 4; ++r)
      rmax[r] = fmaxf(fmaxf(s[0][r], s[1][r]), fmaxf(s[2][r], s[3][r]));
#pragma unroll
    for (int off = 1; off < 16; off <<= 1)
#pragma unroll
      for (int r = 0; r < 4; ++r)
        rmax[r] = fmaxf(rmax[r], __shfl_xor(rmax[r], off));

    // defer-max: only rescale when max grew by > 8 (in log2 units)
    bool need = (rmax[0] > mrun[0] + 8.f) || (rmax[1] > mrun[1] + 8.f) ||
                (rmax[2] > mrun[2] + 8.f) || (rmax[3] > mrun[3] + 8.f);
    if (__any(need)) {
#pragma unroll
      for (int r = 0; r < 4; ++r) {
        float mnew = fmaxf(mrun[r], rmax[r]);
        float al = vexp2(mrun[r] - mnew);
        mrun[r] = mnew;
        lsum[r] *= al;
        acc[0][r] *= al; acc[1][r] *= al; acc[2][r] *= al; acc[3][r] *= al;
      }
    }

    // p = 2^(s - m); pack pairs to bf16 via v_cvt_pk; partial lsum per lane
#pragma unroll
    for (int r = 0; r < 4; ++r) {
      float p0 = vexp2(s[0][r] - mrun[r]);
      float p1 = vexp2(s[1][r] - mrun[r]);
      float p2 = vexp2(s[2][r] - mrun[r]);
      float p3 = vexp2(s[3][r] - mrun[r]);
      lsum[r] += (p0 + p1) + (p2 + p3);
      unsigned pk01 = cvtpk_bf16(p0, p1);
      unsigned pk23 = cvtpk_bf16(p2, p3);
      unsigned short* prow = (unsigned short*)&Pt[wid][(g*4 + r)*72];
      prow[lr]      = (unsigned short)pk01;
      prow[16 + lr] = (unsigned short)(pk01 >> 16);
      prow[32 + lr] = (unsigned short)pk23;
      prow[48 + lr] = (unsigned short)(pk23 >> 16);
    }

    // PV: acc[q][d] += P[q][k] * V^T[d][k]
    s16x8 pa0 = *(const s16x8*)&Pt[wid][lr*72 + g*8];
    s16x8 pa1 = *(const s16x8*)&Pt[wid][lr*72 + 32 + g*8];
#pragma unroll
    for (int db = 0; db < 4; ++db) {
      s16x8 vb0 = *(const s16x8*)&Vt[(db*16 + lr)*72 + g*8];
      s16x8 vb1 = *(const s16x8*)&Vt[(db*16 + lr)*72 + 32 + g*8];
      acc[db] = mfma16(pa0, vb0, acc[db]);
      acc[db] = mfma16(pa1, vb1, acc[db]);
    }
    __syncthreads();
  }

#pragma unroll
  for (int off = 1; off < 16; off <<= 1)
#pragma unroll
    for (int r = 0; r < 4; ++r)
      lsum[r] += __shfl_xor(lsum[r], off);

#pragma unroll
  for (int r = 0; r < 4; ++r) {
    float inv = 1.0f / lsum[r];
    size_t row = (size_t)(b*NN + q0 + g*4 + r);
#pragma unroll
    for (int db = 0; db < 4; ++db)
      attnb[row*HH + (bh & 15)*64 + db*16 + lr] = f2bf(acc[db][r]*inv);
  }
}

// ---------------- output projection (fp32 out) ----------------
__global__ __launch_bounds__(256) void outproj_kernel(
    const short* __restrict__ attnb, const short* __restrict__ wob,
    float* __restrict__ out) {
  __shared__ short smem[10240];
  const int bm = blockIdx.y, bn = blockIdx.x;
  f32x4 acc[4][4];
  gemm128_core(attnb, wob, bm, bn, smem, acc);
  const int tid = threadIdx.x, lane = tid & 63, wid = tid >> 6;
  const int wr = wid >> 1, wc = wid & 1, g = lane >> 4, lr = lane & 15;
  const int m0 = bm*128 + wr*64;
  const int c0 = bn*128 + wc*64;
#pragma unroll
  for (int mf = 0; mf < 4; ++mf)
#pragma unroll
    for (int r = 0; r < 4; ++r) {
      int m = m0 + mf*16 + g*4 + r;
      float* po = out + (size_t)m*HH + c0;
#pragma unroll
      for (int nf = 0; nf < 4; ++nf)
        po[nf*16 + lr] = acc[mf][nf][r];
    }
}

extern "C" void kernel_launch(void* const* d_in, const int* in_sizes, int n_in,
                              void* d_out, int out_size, void* d_ws, size_t ws_size,
                              hipStream_t stream) {
  const float* feat = (const float*)d_in[0];
  const int*   mask = (const int*)d_in[1];
  const float* wq   = (const float*)d_in[2];
  const float* wk   = (const float*)d_in[3];
  const float* wv   = (const float*)d_in[4];
  const float* wo   = (const float*)d_in[5];
  float* out = (float*)d_out;

  char* ws = (char*)d_ws;
  size_t off = 0;
  short* fbf = (short*)(ws + off); off += (size_t)BB*NN*HH*2;
  short* wqb = (short*)(ws + off); off += (size_t)HH*HH*2;
  short* wkb = (short*)(ws + off); off += (size_t)HH*HH*2;
  short* wvb = (short*)(ws + off); off += (size_t)HH*HH*2;
  short* wob = (short*)(ws + off); off += (size_t)HH*HH*2;
  float* cosb = (float*)(ws + off); off += (size_t)NN*32*4;
  float* sinb = (float*)(ws + off); off += (size_t)NN*32*4;
  float* mbias = (float*)(ws + off); off += (size_t)BB*NN*4;
  short* qbuf = (short*)(ws + off); off += (size_t)BB*NN*HH*2;
  short* kbuf = (short*)(ws + off); off += (size_t)BB*NN*HH*2;
  short* vtbuf = (short*)(ws + off); off += (size_t)BB*NN*HH*2;
  short* attnb = (short*)(ws + off); off += (size_t)BB*NN*HH*2;

  prep_kernel<<<1024, 256, 0, stream>>>(feat, mask, wq, wk, wv, wo,
                                        fbf, wqb, wkb, wvb, wob, cosb, sinb, mbias);
  qkv_kernel<<<dim3(HH/128, BB*NN/128, 3), 256, 0, stream>>>(
      fbf, wqb, wkb, wvb, cosb, sinb, qbuf, kbuf, vtbuf);
  attn_kernel<<<dim3(NN/64, BB*NHEAD), 256, 0, stream>>>(
      qbuf, kbuf, vtbuf, mbias, attnb);
  outproj_kernel<<<dim3(HH/128, BB*NN/128), 256, 0, stream>>>(attnb, wob, out);
}

// Round 3
// 141.166 us; speedup vs baseline: 1.4315x; 1.1739x over previous
//
#include <hip/hip_runtime.h>
#include <hip/hip_bf16.h>

typedef __attribute__((ext_vector_type(4))) float f32x4;
typedef __attribute__((ext_vector_type(8))) short s16x8;
typedef __attribute__((ext_vector_type(4))) short s16x4;

#define BB 2
#define NN 2048
#define HH 1024
#define NHEAD 16
#define HDIM 64

__device__ __forceinline__ short f2bf(float f) {
  union { float f; unsigned u; } v; v.f = f;
  unsigned r = v.u + 0x7fffu + ((v.u >> 16) & 1u);
  return (short)(r >> 16);
}

__device__ __forceinline__ f32x4 zf4() { f32x4 z; z[0]=0.f; z[1]=0.f; z[2]=0.f; z[3]=0.f; return z; }

__device__ __forceinline__ f32x4 mfma16(s16x8 a, s16x8 b, f32x4 c) {
  return __builtin_amdgcn_mfma_f32_16x16x32_bf16(a, b, c, 0, 0, 0);
}

__device__ __forceinline__ s16x4 cvt4(f32x4 v) {
  s16x4 o; o[0]=f2bf(v[0]); o[1]=f2bf(v[1]); o[2]=f2bf(v[2]); o[3]=f2bf(v[3]); return o;
}

__device__ __forceinline__ float vexp2(float x) {
  float r; asm("v_exp_f32 %0, %1" : "=v"(r) : "v"(x)); return r;
}

__device__ __forceinline__ float vrcp(float x) {
  float r; asm("v_rcp_f32 %0, %1" : "=v"(r) : "v"(x)); return r;
}

__device__ __forceinline__ unsigned cvtpk_bf16(float lo, float hi) {
  unsigned r; asm("v_cvt_pk_bf16_f32 %0, %1, %2" : "=v"(r) : "v"(lo), "v"(hi)); return r;
}

// ---------------- prep: fp32->bf16 conversions + rope tables + mask bias ----------------
__global__ __launch_bounds__(256) void prep_kernel(
    const float* __restrict__ feat, const int* __restrict__ mask,
    const float* __restrict__ wq, const float* __restrict__ wk,
    const float* __restrict__ wv, const float* __restrict__ wo,
    short* __restrict__ fbf, short* __restrict__ wqb, short* __restrict__ wkb,
    short* __restrict__ wvb, short* __restrict__ wob,
    float* __restrict__ cosb, float* __restrict__ sinb,
    float* __restrict__ mbias, int* __restrict__ mseg) {
  const int tid = blockIdx.x * blockDim.x + threadIdx.x;
  const int nth = gridDim.x * blockDim.x;
  const int NF4 = BB*NN*HH/4;
  for (int i = tid; i < NF4; i += nth)
    ((s16x4*)fbf)[i] = cvt4(((const f32x4*)feat)[i]);
  const int NW4 = HH*HH/4;
  for (int i = tid; i < NW4; i += nth) {
    ((s16x4*)wqb)[i] = cvt4(((const f32x4*)wq)[i]);
    ((s16x4*)wkb)[i] = cvt4(((const f32x4*)wk)[i]);
    ((s16x4*)wvb)[i] = cvt4(((const f32x4*)wv)[i]);
    ((s16x4*)wob)[i] = cvt4(((const f32x4*)wo)[i]);
  }
  // rope table: cos/sin[pos][f], f in [0,32), inv_freq = 10000^(-f/32)
  for (int i = tid; i < NN*32; i += nth) {
    int pos = i >> 5, f = i & 31;
    float inv = __expf(-(float)f * 0.28782313662425572f);  // ln(10000)/32
    float ang = (float)pos * inv;
    float s, c;
    sincosf(ang, &s, &c);
    cosb[i] = c; sinb[i] = s;
  }
  // mask bias: 0 if valid, -1e30 if masked (finite so s-m never cancels to 0)
  for (int i = tid; i < BB*NN; i += nth)
    mbias[i] = mask[i] ? 0.f : -1.0e30f;
  // per-64-key segment flag: 1 if ANY key in segment is masked
  for (int i = tid; i < BB*(NN/64); i += nth) {
    int bb = i / (NN/64), sg = i % (NN/64);
    int any = 0;
    for (int j = 0; j < 64; ++j) any |= (mask[bb*NN + sg*64 + j] == 0);
    mseg[i] = any;
  }
}

// ---------------- GEMM core: C = A(bf16 [M,1024]) @ W^T (W bf16 [1024,1024] row-major [o][k]) ----
__device__ __forceinline__ void gemm128_core(
    const short* __restrict__ A, const short* __restrict__ W,
    int bm, int bn, short* smem, f32x4 acc[4][4]) {
  const int tid = threadIdx.x;
  const int lane = tid & 63, wid = tid >> 6;
  const int wr = wid >> 1, wc = wid & 1;
  const int g = lane >> 4, lr = lane & 15;
  short* At = smem;          // [128][40]
  short* Bt = smem + 5120;   // [128][40]
#pragma unroll
  for (int i = 0; i < 4; ++i)
#pragma unroll
    for (int j = 0; j < 4; ++j) acc[i][j] = zf4();

  const int srow = tid >> 2;        // 0..63
  const int scol = (tid & 3) * 8;   // 0,8,16,24
  const short* Aptr = A + (size_t)(bm*128 + srow) * HH + scol;
  const short* Wptr = W + (size_t)(bn*128 + srow) * HH + scol;

  s16x8 ra0 = *(const s16x8*)(Aptr);
  s16x8 ra1 = *(const s16x8*)(Aptr + 64*HH);
  s16x8 rb0 = *(const s16x8*)(Wptr);
  s16x8 rb1 = *(const s16x8*)(Wptr + 64*HH);

  const int NT = HH / 32;
  for (int t = 0; t < NT; ++t) {
    *(s16x8*)&At[srow*40 + scol]      = ra0;
    *(s16x8*)&At[(srow+64)*40 + scol] = ra1;
    *(s16x8*)&Bt[srow*40 + scol]      = rb0;
    *(s16x8*)&Bt[(srow+64)*40 + scol] = rb1;
    __syncthreads();
    if (t + 1 < NT) {
      const short* ap = Aptr + (t+1)*32;
      const short* wp = Wptr + (t+1)*32;
      ra0 = *(const s16x8*)(ap);
      ra1 = *(const s16x8*)(ap + 64*HH);
      rb0 = *(const s16x8*)(wp);
      rb1 = *(const s16x8*)(wp + 64*HH);
    }
    s16x8 af[4], bf[4];
#pragma unroll
    for (int mf = 0; mf < 4; ++mf)
      af[mf] = *(const s16x8*)&At[(wr*64 + mf*16 + lr)*40 + g*8];
#pragma unroll
    for (int nf = 0; nf < 4; ++nf)
      bf[nf] = *(const s16x8*)&Bt[(wc*64 + nf*16 + lr)*40 + g*8];
#pragma unroll
    for (int mf = 0; mf < 4; ++mf)
#pragma unroll
      for (int nf = 0; nf < 4; ++nf)
        acc[mf][nf] = mfma16(af[mf], bf[nf], acc[mf][nf]);
    __syncthreads();
  }
}

// ---------------- QKV projection + RoPE + layout ----------------
// z=0: Q (rope, *0.125*log2e) -> [b,h,n,d] ; z=1: K (rope) -> [b,h,n,d] ; z=2: V -> V^T [b,h,d,n]
__global__ __launch_bounds__(256) void qkv_kernel(
    const short* __restrict__ fbf, const short* __restrict__ wqb,
    const short* __restrict__ wkb, const short* __restrict__ wvb,
    const float* __restrict__ cosb, const float* __restrict__ sinb,
    short* __restrict__ qb, short* __restrict__ kb, short* __restrict__ vtb) {
  __shared__ short smem[18432];
  const int bm = blockIdx.y, bn = blockIdx.x, z = blockIdx.z;
  const short* W = (z == 0) ? wqb : ((z == 1) ? wkb : wvb);
  f32x4 acc[4][4];
  gemm128_core(fbf, W, bm, bn, smem, acc);

  const int tid = threadIdx.x, lane = tid & 63, wid = tid >> 6;
  const int wr = wid >> 1, wc = wid & 1, g = lane >> 4, lr = lane & 15;
  const int head = bn*2 + wc;
  const int m0 = bm*128 + wr*64;
  const int b = m0 / NN;

  if (z < 2) {
    short* dst = (z == 0) ? qb : kb;
    // Q: fold 1/sqrt(d) AND log2(e) (we use exp2 in attention)
    const float scale = (z == 0) ? 0.18033688011112042f : 1.0f;
#pragma unroll
    for (int mf = 0; mf < 4; ++mf) {
#pragma unroll
      for (int r = 0; r < 4; ++r) {
        int m = m0 + mf*16 + g*4 + r;
        int n = m & (NN - 1);
        float c0 = cosb[n*32 + lr],      s0 = sinb[n*32 + lr];
        float c1 = cosb[n*32 + 16 + lr], s1 = sinb[n*32 + 16 + lr];
        float v0 = acc[mf][0][r], v1 = acc[mf][1][r];
        float v2 = acc[mf][2][r], v3 = acc[mf][3][r];
        float o0 = (v0*c0 - v2*s0) * scale;
        float o1 = (v1*c1 - v3*s1) * scale;
        float o2 = (v2*c0 + v0*s0) * scale;
        float o3 = (v3*c1 + v1*s1) * scale;
        size_t base = ((size_t)(b*NHEAD + head)*NN + n)*HDIM;
        dst[base +  0 + lr] = f2bf(o0);
        dst[base + 16 + lr] = f2bf(o1);
        dst[base + 32 + lr] = f2bf(o2);
        dst[base + 48 + lr] = f2bf(o3);
      }
    }
  } else {
    __syncthreads();
    short* tp = smem + wid*4608;  // [64][72]
#pragma unroll
    for (int mf = 0; mf < 4; ++mf)
#pragma unroll
      for (int nf = 0; nf < 4; ++nf)
#pragma unroll
        for (int r = 0; r < 4; ++r)
          tp[(nf*16 + lr)*72 + mf*16 + g*4 + r] = f2bf(acc[mf][nf][r]);
    __syncthreads();
    const int nbase = m0 & (NN - 1);
    size_t vbase = ((size_t)(b*NHEAD + head)*HDIM)*NN;
#pragma unroll
    for (int it = 0; it < 8; ++it) {
      int j  = it*8 + (lane >> 3);
      int ns = (lane & 7)*8;
      s16x8 vv = *(const s16x8*)&tp[j*72 + ns];
      *(s16x8*)&vtb[vbase + (size_t)j*NN + nbase + ns] = vv;
    }
  }
}

// ---------------- fused flash attention (swapped QK^T: lane-local softmax rows) ----------------
// grid: (N/64, B*NHEAD); 4 waves, each 16 q rows; 64-key steps
__global__ __launch_bounds__(256) void attn_kernel(
    const short* __restrict__ qb, const short* __restrict__ kb,
    const short* __restrict__ vtb, const float* __restrict__ mbias,
    const int* __restrict__ mseg,
    short* __restrict__ attnb) {
  __shared__ short Kt[64*72];                      // [64 keys][64 d + pad]
  __shared__ short Vt[64*72];                      // [64 d][64 keys + pad]
  __shared__ __align__(16) unsigned Pd[4][16*36];  // per-wave [16 q][32 dwords + pad]
  const int tid = threadIdx.x, lane = tid & 63, wid = tid >> 6;
  const int g = lane >> 4, lr = lane & 15;
  const int bh = blockIdx.y; const int b = bh >> 4;
  const int q0 = blockIdx.x*64 + wid*16;

  // Q regs: A-layout image == B-operand image (col=q=lr, k=d=g*8..+8)
  const short* qp = qb + ((size_t)bh*NN + q0 + lr)*HDIM + g*8;
  s16x8 qf0 = *(const s16x8*)(qp);
  s16x8 qf1 = *(const s16x8*)(qp + 32);

  f32x4 acc[4];
#pragma unroll
  for (int i = 0; i < 4; ++i) acc[i] = zf4();
  float mrun = -3.0e38f, lsum = 0.f;

  const int sr = tid >> 2;            // 0..63
  const int sc = (tid & 3) * 16;      // 0,16,32,48
  const short* kp = kb + (size_t)bh*NN*HDIM + (size_t)sr*HDIM + sc;
  const short* vp = vtb + ((size_t)bh*HDIM + sr)*NN + sc;
  const float* mb = mbias + b*NN;
  const int* msp = mseg + b*(NN/64);

  s16x8 kr0 = *(const s16x8*)(kp);
  s16x8 kr1 = *(const s16x8*)(kp + 8);
  s16x8 vr0 = *(const s16x8*)(vp);
  s16x8 vr1 = *(const s16x8*)(vp + 8);

  for (int k0 = 0; k0 < NN; k0 += 64) {
    *(s16x8*)&Kt[sr*72 + sc]     = kr0;
    *(s16x8*)&Kt[sr*72 + sc + 8] = kr1;
    *(s16x8*)&Vt[sr*72 + sc]     = vr0;
    *(s16x8*)&Vt[sr*72 + sc + 8] = vr1;
    __syncthreads();
    if (k0 + 64 < NN) {  // prefetch next tile into regs (overlaps compute)
      kp += 64*HDIM; vp += 64;
      kr0 = *(const s16x8*)(kp);
      kr1 = *(const s16x8*)(kp + 8);
      vr0 = *(const s16x8*)(vp);
      vr1 = *(const s16x8*)(vp + 8);
    }

    // S^T = K @ Q^T : lane holds q=lr, keys kg*16 + g*4 + r
    f32x4 s[4];
    __builtin_amdgcn_s_setprio(1);
#pragma unroll
    for (int kg = 0; kg < 4; ++kg) {
      s16x8 ka0 = *(const s16x8*)&Kt[(kg*16 + lr)*72 + g*8];
      s16x8 ka1 = *(const s16x8*)&Kt[(kg*16 + lr)*72 + 32 + g*8];
      s[kg] = mfma16(ka1, qf1, mfma16(ka0, qf0, zf4()));
    }
    __builtin_amdgcn_s_setprio(0);

    if (msp[k0 >> 6]) {  // rare: some key in this segment masked
#pragma unroll
      for (int kg = 0; kg < 4; ++kg) {
        f32x4 bi = *(const f32x4*)&mb[k0 + kg*16 + g*4];
#pragma unroll
        for (int r = 0; r < 4; ++r) s[kg][r] += bi[r];
      }
    }

    // row max: in-reg tree over 16, then across the 4 g-groups
    float m0a = fmaxf(fmaxf(s[0][0], s[0][1]), fmaxf(s[0][2], s[0][3]));
    float m1a = fmaxf(fmaxf(s[1][0], s[1][1]), fmaxf(s[1][2], s[1][3]));
    float m2a = fmaxf(fmaxf(s[2][0], s[2][1]), fmaxf(s[2][2], s[2][3]));
    float m3a = fmaxf(fmaxf(s[3][0], s[3][1]), fmaxf(s[3][2], s[3][3]));
    float rmax = fmaxf(fmaxf(m0a, m1a), fmaxf(m2a, m3a));
    rmax = fmaxf(rmax, __shfl_xor(rmax, 16));
    rmax = fmaxf(rmax, __shfl_xor(rmax, 32));

    // defer-max: rescale only when max grew by > 8 (log2 units)
    if (__any(rmax > mrun + 8.f)) {
      float mnew = fmaxf(mrun, rmax);
      float al = vexp2(mrun - mnew);
      mrun = mnew;
      lsum *= al;
      float alr[4];
#pragma unroll
      for (int r = 0; r < 4; ++r)
        alr[r] = __shfl(al, (lane & 48) | (g*4 + r));
#pragma unroll
      for (int db = 0; db < 4; ++db)
#pragma unroll
        for (int r = 0; r < 4; ++r) acc[db][r] *= alr[r];
    }

    // p = 2^(s - m); all 16 values share this lane's q => scalar bookkeeping
#pragma unroll
    for (int kg = 0; kg < 4; ++kg) {
      float p0 = vexp2(s[kg][0] - mrun);
      float p1 = vexp2(s[kg][1] - mrun);
      float p2 = vexp2(s[kg][2] - mrun);
      float p3 = vexp2(s[kg][3] - mrun);
      lsum += (p0 + p1) + (p2 + p3);
      // keys kg*16+g*4+{0,1} and {2,3} are ADJACENT -> dword stores
      unsigned* prow = &Pd[wid][lr*36 + kg*8 + g*2];
      prow[0] = cvtpk_bf16(p0, p1);
      prow[1] = cvtpk_bf16(p2, p3);
    }

    // PV: A = P[q=lr][k], read back as b128
    s16x8 pa0 = *(const s16x8*)&Pd[wid][lr*36 + g*4];
    s16x8 pa1 = *(const s16x8*)&Pd[wid][lr*36 + 16 + g*4];
    __builtin_amdgcn_s_setprio(1);
#pragma unroll
    for (int db = 0; db < 4; ++db) {
      s16x8 vb0 = *(const s16x8*)&Vt[(db*16 + lr)*72 + g*8];
      s16x8 vb1 = *(const s16x8*)&Vt[(db*16 + lr)*72 + 32 + g*8];
      acc[db] = mfma16(pa0, vb0, acc[db]);
      acc[db] = mfma16(pa1, vb1, acc[db]);
    }
    __builtin_amdgcn_s_setprio(0);
    __syncthreads();
  }

  // final: lsum reduce across g-groups, redistribute 1/lsum to PV layout (q=g*4+r)
  lsum += __shfl_xor(lsum, 16);
  lsum += __shfl_xor(lsum, 32);
  float inv = vrcp(lsum);
  float invr[4];
#pragma unroll
  for (int r = 0; r < 4; ++r)
    invr[r] = __shfl(inv, (lane & 48) | (g*4 + r));
#pragma unroll
  for (int r = 0; r < 4; ++r) {
    size_t row = (size_t)(b*NN + q0 + g*4 + r);
#pragma unroll
    for (int db = 0; db < 4; ++db)
      attnb[row*HH + (bh & 15)*64 + db*16 + lr] = f2bf(acc[db][r]*invr[r]);
  }
}

// ---------------- output projection (fp32 out) ----------------
__global__ __launch_bounds__(256) void outproj_kernel(
    const short* __restrict__ attnb, const short* __restrict__ wob,
    float* __restrict__ out) {
  __shared__ short smem[10240];
  const int bm = blockIdx.y, bn = blockIdx.x;
  f32x4 acc[4][4];
  gemm128_core(attnb, wob, bm, bn, smem, acc);
  const int tid = threadIdx.x, lane = tid & 63, wid = tid >> 6;
  const int wr = wid >> 1, wc = wid & 1, g = lane >> 4, lr = lane & 15;
  const int m0 = bm*128 + wr*64;
  const int c0 = bn*128 + wc*64;
#pragma unroll
  for (int mf = 0; mf < 4; ++mf)
#pragma unroll
    for (int r = 0; r < 4; ++r) {
      int m = m0 + mf*16 + g*4 + r;
      float* po = out + (size_t)m*HH + c0;
#pragma unroll
      for (int nf = 0; nf < 4; ++nf)
        po[nf*16 + lr] = acc[mf][nf][r];
    }
}

extern "C" void kernel_launch(void* const* d_in, const int* in_sizes, int n_in,
                              void* d_out, int out_size, void* d_ws, size_t ws_size,
                              hipStream_t stream) {
  const float* feat = (const float*)d_in[0];
  const int*   mask = (const int*)d_in[1];
  const float* wq   = (const float*)d_in[2];
  const float* wk   = (const float*)d_in[3];
  const float* wv   = (const float*)d_in[4];
  const float* wo   = (const float*)d_in[5];
  float* out = (float*)d_out;

  char* ws = (char*)d_ws;
  size_t off = 0;
  short* fbf = (short*)(ws + off); off += (size_t)BB*NN*HH*2;
  short* wqb = (short*)(ws + off); off += (size_t)HH*HH*2;
  short* wkb = (short*)(ws + off); off += (size_t)HH*HH*2;
  short* wvb = (short*)(ws + off); off += (size_t)HH*HH*2;
  short* wob = (short*)(ws + off); off += (size_t)HH*HH*2;
  float* cosb = (float*)(ws + off); off += (size_t)NN*32*4;
  float* sinb = (float*)(ws + off); off += (size_t)NN*32*4;
  float* mbias = (float*)(ws + off); off += (size_t)BB*NN*4;
  int* msegb = (int*)(ws + off); off += (size_t)BB*(NN/64)*4;
  short* qbuf = (short*)(ws + off); off += (size_t)BB*NN*HH*2;
  short* kbuf = (short*)(ws + off); off += (size_t)BB*NN*HH*2;
  short* vtbuf = (short*)(ws + off); off += (size_t)BB*NN*HH*2;
  short* attnb = (short*)(ws + off); off += (size_t)BB*NN*HH*2;

  prep_kernel<<<1024, 256, 0, stream>>>(feat, mask, wq, wk, wv, wo,
                                        fbf, wqb, wkb, wvb, wob, cosb, sinb,
                                        mbias, msegb);
  qkv_kernel<<<dim3(HH/128, BB*NN/128, 3), 256, 0, stream>>>(
      fbf, wqb, wkb, wvb, cosb, sinb, qbuf, kbuf, vtbuf);
  attn_kernel<<<dim3(NN/64, BB*NHEAD), 256, 0, stream>>>(
      qbuf, kbuf, vtbuf, mbias, msegb, attnb);
  outproj_kernel<<<dim3(HH/128, BB*NN/128), 256, 0, stream>>>(attnb, wob, out);
}